// Round 5
// baseline (143.928 us; speedup 1.0000x reference)
//
#include <hip/hip_runtime.h>

// PhysicsGuidedAttention: B=2, N=2048, D=768, H=12, Hd=64
// qkv = x @ w_qkv.T ; flash-attn with elevation bias ; out = attn_out @ w_proj.T + b_proj
// R5: attn = 768 blocks (3/CU full residency), KV-parity waves, T14 reg-staging
//     for K AND V (loads stay in flight across barriers), single LDS buffer per
//     parity, no launch-bounds min-occupancy. GEMMs = R4 2-phase dbuf (kept).

typedef __attribute__((ext_vector_type(8))) short bf16x8;   // 8 bf16 = 4 VGPRs
typedef __attribute__((ext_vector_type(4))) float f32x4;
typedef __attribute__((ext_vector_type(16))) float f32x16;  // 32x32 accumulator

__device__ __forceinline__ unsigned short f2bf(float f) {
  unsigned int u = __builtin_bit_cast(unsigned int, f);
  u += 0x7fffu + ((u >> 16) & 1u);        // round-to-nearest-even
  return (unsigned short)(u >> 16);
}

__device__ __forceinline__ unsigned cvtpk(float lo, float hi) {
  unsigned r;
  asm("v_cvt_pk_bf16_f32 %0, %1, %2" : "=v"(r) : "v"(lo), "v"(hi));
  return r;
}

__device__ __forceinline__ float exp2v(float x) {
  float r;
  asm("v_exp_f32 %0, %1" : "=v"(r) : "v"(x));
  return r;
}

// XOR swizzle on element index: spreads 128B-stride row slots across banks.
__device__ __forceinline__ int sw8(int row) {
  return ((row ^ (row >> 3)) & 7) << 3;
}

__device__ __forceinline__ void gload16(const unsigned short* g, unsigned short* l) {
  __builtin_amdgcn_global_load_lds(
      (const __attribute__((address_space(1))) unsigned int*)g,
      (__attribute__((address_space(3))) unsigned int*)l, 16, 0, 0);
}

// ---------------------------------------------------------------------------
__global__ __launch_bounds__(256)
void cvt_kernel(const float* __restrict__ in, unsigned short* __restrict__ out, int n8) {
  const int i = blockIdx.x * 256 + threadIdx.x;
  if (i >= n8) return;
  const float4 f0 = ((const float4*)in)[i * 2];
  const float4 f1 = ((const float4*)in)[i * 2 + 1];
  uint4 v;
  v.x = (unsigned)f2bf(f0.x) | ((unsigned)f2bf(f0.y) << 16);
  v.y = (unsigned)f2bf(f0.z) | ((unsigned)f2bf(f0.w) << 16);
  v.z = (unsigned)f2bf(f1.x) | ((unsigned)f2bf(f1.y) << 16);
  v.w = (unsigned)f2bf(f1.z) | ((unsigned)f2bf(f1.w) << 16);
  ((uint4*)out)[i] = v;
}

// ---------------------------------------------------------------------------
// C[M,N] = A[M,K] @ B[N,K]^T, bf16, 128x128 tile, BK=32, 2-phase dbuf pipeline.
template<bool OUT_F32>
__global__ __launch_bounds__(256)
void gemm_bt_bf16(const unsigned short* __restrict__ Ap,
                  const unsigned short* __restrict__ Bp,
                  const float* __restrict__ bias, void* __restrict__ Cp,
                  int M, int N, int K) {
  __shared__ __align__(16) unsigned short lds_a[2][128 * 32];
  __shared__ __align__(16) unsigned short lds_b[2][128 * 32];
  const int t = threadIdx.x;
  const int l = t & 63;
  const int w = t >> 6;
  const int wr = w >> 1, wc = w & 1;
  const int brow = blockIdx.x * 128;
  const int bcol = blockIdx.y * 128;
  const int l15 = l & 15, l4 = l >> 4;

  const int srow = t >> 2;
  const int scol = (t & 3) * 8;
  const unsigned short* ga = Ap + (size_t)(brow + srow) * K + scol;
  const unsigned short* gb = Bp + (size_t)(bcol + srow) * K + scol;

  f32x4 acc[4][4] = {};
  const int nk = K >> 5;

  {
    unsigned short* la = lds_a[0] + w * 512;
    unsigned short* lb = lds_b[0] + w * 512;
    gload16(ga, la);
    gload16(ga + (size_t)64 * K, la + 2048);
    gload16(gb, lb);
    gload16(gb + (size_t)64 * K, lb + 2048);
  }
  __syncthreads();

  int buf = 0;
  for (int kt = 0; kt < nk; ++kt) {
    if (kt + 1 < nk) {
      const size_t ko = (size_t)(kt + 1) * 32;
      unsigned short* la = lds_a[buf ^ 1] + w * 512;
      unsigned short* lb = lds_b[buf ^ 1] + w * 512;
      gload16(ga + ko, la);
      gload16(ga + ko + (size_t)64 * K, la + 2048);
      gload16(gb + ko, lb);
      gload16(gb + ko + (size_t)64 * K, lb + 2048);
    }
    bf16x8 af[4], bfr[4];
#pragma unroll
    for (int i = 0; i < 4; ++i) {
      af[i]  = *(const bf16x8*)&lds_a[buf][(wr * 64 + i * 16 + l15) * 32 + l4 * 8];
      bfr[i] = *(const bf16x8*)&lds_b[buf][(wc * 64 + i * 16 + l15) * 32 + l4 * 8];
    }
#pragma unroll
    for (int i = 0; i < 4; ++i)
#pragma unroll
      for (int j = 0; j < 4; ++j)
        acc[i][j] = __builtin_amdgcn_mfma_f32_16x16x32_bf16(af[i], bfr[j], acc[i][j], 0, 0, 0);
    __syncthreads();
    buf ^= 1;
  }

#pragma unroll
  for (int i = 0; i < 4; ++i)
#pragma unroll
    for (int j = 0; j < 4; ++j)
#pragma unroll
      for (int r = 0; r < 4; ++r) {
        const int row = brow + wr * 64 + i * 16 + l4 * 4 + r;
        const int col = bcol + wc * 64 + j * 16 + l15;
        const float v = acc[i][j][r];
        if constexpr (OUT_F32) {
          ((float*)Cp)[(size_t)row * N + col] = v + bias[col];
        } else {
          ((unsigned short*)Cp)[(size_t)row * N + col] = f2bf(v);
        }
      }
}

// ---------------------------------------------------------------------------
// Flash attention, 32x32x16 MFMA, swapped QK^T, no max-tracking.
// grid = (B*H, N/64); 256 thr = 4 waves: wq = w&1 (q sub-tile of 32 rows),
// par = w>>1 (kv parity: wave-pair does tiles 2s+par, s=0..15).
// Reg-staged K and V (T14: load early, write after read-barrier). Parity
// partials are pure sums (no max-tracking) -> LDS combine at end.
__global__ __launch_bounds__(256)
void attn_kernel(const unsigned short* __restrict__ qkv,
                 const float* __restrict__ elev,
                 const float* __restrict__ alpha_p,
                 unsigned short* __restrict__ aout) {
  __shared__ __align__(16) unsigned short lds_k[2][64 * 64];   // [par][kv][d] swz
  __shared__ __align__(16) unsigned short lds_vt[2][64 * 64];  // [par][d][kv] swz
  __shared__ float lds_ej[2][64];
  __shared__ float lds_linv[2][32];

  const int t = threadIdx.x;
  const int l = t & 63;
  const int w = t >> 6;
  const int wq = w & 1;
  const int par = w >> 1;
  const int l31 = l & 31;
  const int h = l >> 5;
  const int b = blockIdx.x / 12, hd = blockIdx.x % 12;
  const int qw = blockIdx.y * 64 + wq * 32;

  const float cE = fmaxf(alpha_p[0], 0.f) * (1.4426950408889634f * 1e-3f);
  const float c1 = 0.18033688011112042f;   // 0.125 * log2(e)

  const size_t rs = 2304;
  const unsigned short* qbase = qkv + ((size_t)b * 2048) * rs + hd * 64;
  const unsigned short* kbase = qbase + 768;
  const unsigned short* vbase = qbase + 1536;

  bf16x8 qa[4];
  {
    const unsigned short* qp = qbase + (size_t)(qw + l31) * rs + h * 8;
#pragma unroll
    for (int ks = 0; ks < 4; ++ks) qa[ks] = *(const bf16x8*)(qp + ks * 16);
  }
  const float eiv = elev[(size_t)b * 2048 + qw + l31] * cE;

  // staging (128 threads per parity pair, tp = t&127):
  // K: rows kr+16i, cols kc..kc+8 (R3's conflict-free pattern per wave)
  // V: row vr, col halves vh+8i (transpose-write, R3 pattern)
  const int tp = t & 127;
  const int kr = tp >> 3;
  const int kc = (tp & 7) * 8;
  const int vr = tp >> 1;
  const int vh = (tp & 1) * 32;

  uint4 rk[4], rv[4];
  float evn = 0.f;

  f32x16 o[2] = {};
  float psum = 0.f;

  // ---- prologue: load+write tile T0 = par ----
  {
    const int kv0 = par * 64;
#pragma unroll
    for (int i = 0; i < 4; ++i)
      rk[i] = *(const uint4*)(kbase + (size_t)(kv0 + kr + 16 * i) * rs + kc);
#pragma unroll
    for (int i = 0; i < 4; ++i)
      rv[i] = *(const uint4*)(vbase + (size_t)(kv0 + vr) * rs + vh + i * 8);
    if (wq == 0) evn = elev[(size_t)b * 2048 + kv0 + l];
#pragma unroll
    for (int i = 0; i < 4; ++i) {
      const int r = kr + 16 * i;
      *(uint4*)&lds_k[par][r * 64 + (kc ^ sw8(r))] = rk[i];
    }
#pragma unroll
    for (int i = 0; i < 4; ++i) {
      union { uint4 u; unsigned short s[8]; } vu; vu.u = rv[i];
#pragma unroll
      for (int j = 0; j < 8; ++j) {
        const int d = vh + i * 8 + j;
        lds_vt[par][d * 64 + (vr ^ sw8(d))] = vu.s[j];
      }
    }
    if (wq == 0) lds_ej[par][l] = evn * cE;
  }
  __syncthreads();

  for (int s = 0; s < 16; ++s) {
    const bool more = s < 15;
    if (more) {                    // prefetch tile 2(s+1)+par into registers
      const int kvn = (2 * (s + 1) + par) * 64;
#pragma unroll
      for (int i = 0; i < 4; ++i)
        rk[i] = *(const uint4*)(kbase + (size_t)(kvn + kr + 16 * i) * rs + kc);
#pragma unroll
      for (int i = 0; i < 4; ++i)
        rv[i] = *(const uint4*)(vbase + (size_t)(kvn + vr) * rs + vh + i * 8);
      if (wq == 0) evn = elev[(size_t)b * 2048 + kvn + l];
    }

    // --- S^T = K x Q ---
    f32x16 st[2] = {};
    __builtin_amdgcn_s_setprio(1);
#pragma unroll
    for (int kst = 0; kst < 4; ++kst) {
      const int col = kst * 16 + h * 8;
#pragma unroll
      for (int mb = 0; mb < 2; ++mb) {
        const int row = mb * 32 + l31;
        bf16x8 kf = *(const bf16x8*)&lds_k[par][row * 64 + (col ^ sw8(row))];
        st[mb] = __builtin_amdgcn_mfma_f32_32x32x16_bf16(kf, qa[kst], st[mb], 0, 0, 0);
      }
    }
    __builtin_amdgcn_s_setprio(0);

    // --- softmax + in-register P pack ---
    bf16x8 pa[4];
#pragma unroll
    for (int mb = 0; mb < 2; ++mb) {
      float p16[16];
#pragma unroll
      for (int rr = 0; rr < 4; ++rr) {
        const float4 ejq = *(const float4*)&lds_ej[par][mb * 32 + rr * 8 + h * 4];
#pragma unroll
        for (int jl = 0; jl < 4; ++jl) {
          const int r = rr * 4 + jl;
          const float bm = __builtin_amdgcn_fmed3f(ejq[jl] - eiv, 0.f, 14.4269504f);
          const float p = exp2v(__builtin_fmaf(st[mb][r], c1, -bm));
          p16[r] = p;
          psum += p;
        }
      }
#pragma unroll
      for (int ks2 = 0; ks2 < 2; ++ks2) {
        unsigned u0 = cvtpk(p16[ks2 * 8 + 0], p16[ks2 * 8 + 1]);
        unsigned u1 = cvtpk(p16[ks2 * 8 + 2], p16[ks2 * 8 + 3]);
        unsigned v0 = cvtpk(p16[ks2 * 8 + 4], p16[ks2 * 8 + 5]);
        unsigned v1 = cvtpk(p16[ks2 * 8 + 6], p16[ks2 * 8 + 7]);
        asm volatile("v_permlane32_swap_b32 %0, %1" : "+v"(u0), "+v"(v0));
        asm volatile("v_permlane32_swap_b32 %0, %1" : "+v"(u1), "+v"(v1));
        uint4 fr; fr.x = u0; fr.y = u1; fr.z = v0; fr.w = v1;
        pa[mb * 2 + ks2] = __builtin_bit_cast(bf16x8, fr);
      }
    }

    // --- O += P @ V ---
    __builtin_amdgcn_s_setprio(1);
#pragma unroll
    for (int ks = 0; ks < 4; ++ks) {
      const int col = ks * 16 + h * 8;
#pragma unroll
      for (int nb = 0; nb < 2; ++nb) {
        const int row = nb * 32 + l31;
        bf16x8 vf = *(const bf16x8*)&lds_vt[par][row * 64 + (col ^ sw8(row))];
        o[nb] = __builtin_amdgcn_mfma_f32_32x32x16_bf16(pa[ks], vf, o[nb], 0, 0, 0);
      }
    }
    __builtin_amdgcn_s_setprio(0);

    __syncthreads();               // parity pair done reading its buffers
    if (more) {                    // T14 late-write: regs -> LDS
#pragma unroll
      for (int i = 0; i < 4; ++i) {
        const int r = kr + 16 * i;
        *(uint4*)&lds_k[par][r * 64 + (kc ^ sw8(r))] = rk[i];
      }
#pragma unroll
      for (int i = 0; i < 4; ++i) {
        union { uint4 u; unsigned short s[8]; } vu; vu.u = rv[i];
#pragma unroll
        for (int j = 0; j < 8; ++j) {
          const int d = vh + i * 8 + j;
          lds_vt[par][d * 64 + (vr ^ sw8(d))] = vu.s[j];
        }
      }
      if (wq == 0) lds_ej[par][l] = evn * cE;
    }
    __syncthreads();
  }

  // --- combine parity halves (pure sums) + epilogue ---
  psum += __shfl_xor(psum, 32, 64);        // fold h halves (same q col)
  float* xO = (float*)lds_k;               // 16 KB = 4096 f32
  float* xP = (float*)lds_ej;
  if (par == 1) {
#pragma unroll
    for (int nb = 0; nb < 2; ++nb)
#pragma unroll
      for (int rr = 0; rr < 4; ++rr)
#pragma unroll
        for (int jl = 0; jl < 4; ++jl) {
          const int ql = rr * 8 + h * 4 + jl;
          xO[wq * 2048 + ql * 64 + nb * 32 + l31] = o[nb][rr * 4 + jl];
        }
    if (h == 0) xP[wq * 32 + l31] = psum;
  }
  __syncthreads();
  if (par == 0) {
    psum += xP[wq * 32 + l31];
    if (h == 0) lds_linv[wq][l31] = 1.0f / psum;
#pragma unroll
    for (int nb = 0; nb < 2; ++nb)
#pragma unroll
      for (int rr = 0; rr < 4; ++rr)
#pragma unroll
        for (int jl = 0; jl < 4; ++jl) {
          const int ql = rr * 8 + h * 4 + jl;
          o[nb][rr * 4 + jl] += xO[wq * 2048 + ql * 64 + nb * 32 + l31];
        }
  }
  __syncthreads();
  if (par == 0) {
#pragma unroll
    for (int nb = 0; nb < 2; ++nb) {
      const int col = hd * 64 + nb * 32 + l31;
#pragma unroll
      for (int rr = 0; rr < 4; ++rr) {
        const float4 lq = *(const float4*)&lds_linv[wq][rr * 8 + h * 4];
#pragma unroll
        for (int jl = 0; jl < 4; ++jl) {
          const int q = qw + rr * 8 + h * 4 + jl;
          aout[((size_t)b * 2048 + q) * 768 + col] = f2bf(o[nb][rr * 4 + jl] * lq[jl]);
        }
      }
    }
  }
}

extern "C" void kernel_launch(void* const* d_in, const int* in_sizes, int n_in,
                              void* d_out, int out_size, void* d_ws, size_t ws_size,
                              hipStream_t stream) {
  const float* x      = (const float*)d_in[0];   // [2,2048,768]
  const float* elev   = (const float*)d_in[1];   // [2,2048]
  const float* w_qkv  = (const float*)d_in[2];   // [2304,768]
  const float* w_proj = (const float*)d_in[3];   // [768,768]
  const float* b_proj = (const float*)d_in[4];   // [768]
  const float* alpha  = (const float*)d_in[5];   // [1]
  float* out = (float*)d_out;                    // [2,2048,768] f32

  unsigned short* qkvb   = (unsigned short*)d_ws;
  unsigned short* xb     = qkvb + (size_t)4096 * 2304;
  unsigned short* aob    = xb;                          // reuse after gemm1
  unsigned short* wqkvb  = xb + (size_t)4096 * 768;
  unsigned short* wprojb = wqkvb;                       // reuse after gemm1

  cvt_kernel<<<(4096 * 768 / 8 + 255) / 256, 256, 0, stream>>>(x, xb, 4096 * 768 / 8);
  cvt_kernel<<<(2304 * 768 / 8 + 255) / 256, 256, 0, stream>>>(w_qkv, wqkvb, 2304 * 768 / 8);

  gemm_bt_bf16<false><<<dim3(32, 18), 256, 0, stream>>>(
      xb, wqkvb, nullptr, qkvb, 4096, 2304, 768);

  cvt_kernel<<<(768 * 768 / 8 + 255) / 256, 256, 0, stream>>>(w_proj, wprojb, 768 * 768 / 8);

  attn_kernel<<<dim3(24, 32), 256, 0, stream>>>(qkvb, elev, alpha, aob);

  gemm_bt_bf16<true><<<dim3(32, 6), 256, 0, stream>>>(
      aob, wprojb, b_proj, out, 4096, 768, 768);
}

// Round 7
// 132.737 us; speedup vs baseline: 1.0843x; 1.0843x over previous
//
#include <hip/hip_runtime.h>

// PhysicsGuidedAttention: B=2, N=2048, D=768, H=12, Hd=64
// qkv = x @ w_qkv.T ; flash-attn with elevation bias ; out = attn_out @ w_proj.T + b_proj
// R7: R6 structure (2-wave/128-thr blocks, 768 blocks = exactly 3/CU even,
//     dbuf + T14 reg-staging, 1 barrier/iter, swapped QK^T, no-max softmax,
//     in-reg P) but V staging reverted to the R3/R5-proven scalar transpose
//     write into swizzled lds_vt[d][kv] (the R6 tr_b16 layout was wrong).
//     GEMMs = 2-phase dbuf pipeline. cvt x+wqkv merged.

typedef __attribute__((ext_vector_type(8))) short bf16x8;   // 8 bf16 = 4 VGPRs
typedef __attribute__((ext_vector_type(4))) float f32x4;
typedef __attribute__((ext_vector_type(16))) float f32x16;  // 32x32 accumulator

__device__ __forceinline__ unsigned short f2bf(float f) {
  unsigned int u = __builtin_bit_cast(unsigned int, f);
  u += 0x7fffu + ((u >> 16) & 1u);        // round-to-nearest-even
  return (unsigned short)(u >> 16);
}

__device__ __forceinline__ unsigned cvtpk(float lo, float hi) {
  unsigned r;
  asm("v_cvt_pk_bf16_f32 %0, %1, %2" : "=v"(r) : "v"(lo), "v"(hi));
  return r;
}

__device__ __forceinline__ float exp2v(float x) {
  float r;
  asm("v_exp_f32 %0, %1" : "=v"(r) : "v"(x));
  return r;
}

// XOR swizzle on element index: spreads 128B-stride row slots across banks.
__device__ __forceinline__ int sw8(int row) {
  return ((row ^ (row >> 3)) & 7) << 3;
}

__device__ __forceinline__ void gload16(const unsigned short* g, unsigned short* l) {
  __builtin_amdgcn_global_load_lds(
      (const __attribute__((address_space(1))) unsigned int*)g,
      (__attribute__((address_space(3))) unsigned int*)l, 16, 0, 0);
}

// ---------------------------------------------------------------------------
// f32 -> bf16 converts for x and w_qkv in one launch.
__global__ __launch_bounds__(256)
void cvt2_kernel(const float* __restrict__ a, unsigned short* __restrict__ ao, int na8,
                 const float* __restrict__ b, unsigned short* __restrict__ bo, int nb8) {
  int i = blockIdx.x * 256 + threadIdx.x;
  const float* src; unsigned short* dst;
  if (i < na8) { src = a; dst = ao; }
  else {
    i -= na8;
    if (i >= nb8) return;
    src = b; dst = bo;
  }
  const float4 f0 = ((const float4*)src)[i * 2];
  const float4 f1 = ((const float4*)src)[i * 2 + 1];
  uint4 v;
  v.x = (unsigned)f2bf(f0.x) | ((unsigned)f2bf(f0.y) << 16);
  v.y = (unsigned)f2bf(f0.z) | ((unsigned)f2bf(f0.w) << 16);
  v.z = (unsigned)f2bf(f1.x) | ((unsigned)f2bf(f1.y) << 16);
  v.w = (unsigned)f2bf(f1.z) | ((unsigned)f2bf(f1.w) << 16);
  ((uint4*)dst)[i] = v;
}

__global__ __launch_bounds__(256)
void cvt_kernel(const float* __restrict__ in, unsigned short* __restrict__ out, int n8) {
  const int i = blockIdx.x * 256 + threadIdx.x;
  if (i >= n8) return;
  const float4 f0 = ((const float4*)in)[i * 2];
  const float4 f1 = ((const float4*)in)[i * 2 + 1];
  uint4 v;
  v.x = (unsigned)f2bf(f0.x) | ((unsigned)f2bf(f0.y) << 16);
  v.y = (unsigned)f2bf(f0.z) | ((unsigned)f2bf(f0.w) << 16);
  v.z = (unsigned)f2bf(f1.x) | ((unsigned)f2bf(f1.y) << 16);
  v.w = (unsigned)f2bf(f1.z) | ((unsigned)f2bf(f1.w) << 16);
  ((uint4*)out)[i] = v;
}

// ---------------------------------------------------------------------------
// C[M,N] = A[M,K] @ B[N,K]^T, bf16, 128x128 tile, BK=32, 2-phase dbuf pipeline.
template<bool OUT_F32>
__global__ __launch_bounds__(256)
void gemm_bt_bf16(const unsigned short* __restrict__ Ap,
                  const unsigned short* __restrict__ Bp,
                  const float* __restrict__ bias, void* __restrict__ Cp,
                  int M, int N, int K) {
  __shared__ __align__(16) unsigned short lds_a[2][128 * 32];
  __shared__ __align__(16) unsigned short lds_b[2][128 * 32];
  const int t = threadIdx.x;
  const int l = t & 63;
  const int w = t >> 6;
  const int wr = w >> 1, wc = w & 1;
  const int brow = blockIdx.x * 128;
  const int bcol = blockIdx.y * 128;
  const int l15 = l & 15, l4 = l >> 4;

  const int srow = t >> 2;
  const int scol = (t & 3) * 8;
  const unsigned short* ga = Ap + (size_t)(brow + srow) * K + scol;
  const unsigned short* gb = Bp + (size_t)(bcol + srow) * K + scol;

  f32x4 acc[4][4] = {};
  const int nk = K >> 5;

  {
    unsigned short* la = lds_a[0] + w * 512;
    unsigned short* lb = lds_b[0] + w * 512;
    gload16(ga, la);
    gload16(ga + (size_t)64 * K, la + 2048);
    gload16(gb, lb);
    gload16(gb + (size_t)64 * K, lb + 2048);
  }
  __syncthreads();

  int buf = 0;
  for (int kt = 0; kt < nk; ++kt) {
    if (kt + 1 < nk) {
      const size_t ko = (size_t)(kt + 1) * 32;
      unsigned short* la = lds_a[buf ^ 1] + w * 512;
      unsigned short* lb = lds_b[buf ^ 1] + w * 512;
      gload16(ga + ko, la);
      gload16(ga + ko + (size_t)64 * K, la + 2048);
      gload16(gb + ko, lb);
      gload16(gb + ko + (size_t)64 * K, lb + 2048);
    }
    bf16x8 af[4], bfr[4];
#pragma unroll
    for (int i = 0; i < 4; ++i) {
      af[i]  = *(const bf16x8*)&lds_a[buf][(wr * 64 + i * 16 + l15) * 32 + l4 * 8];
      bfr[i] = *(const bf16x8*)&lds_b[buf][(wc * 64 + i * 16 + l15) * 32 + l4 * 8];
    }
#pragma unroll
    for (int i = 0; i < 4; ++i)
#pragma unroll
      for (int j = 0; j < 4; ++j)
        acc[i][j] = __builtin_amdgcn_mfma_f32_16x16x32_bf16(af[i], bfr[j], acc[i][j], 0, 0, 0);
    __syncthreads();
    buf ^= 1;
  }

#pragma unroll
  for (int i = 0; i < 4; ++i)
#pragma unroll
    for (int j = 0; j < 4; ++j)
#pragma unroll
      for (int r = 0; r < 4; ++r) {
        const int row = brow + wr * 64 + i * 16 + l4 * 4 + r;
        const int col = bcol + wc * 64 + j * 16 + l15;
        const float v = acc[i][j][r];
        if constexpr (OUT_F32) {
          ((float*)Cp)[(size_t)row * N + col] = v + bias[col];
        } else {
          ((unsigned short*)Cp)[(size_t)row * N + col] = f2bf(v);
        }
      }
}

// ---------------------------------------------------------------------------
// Flash attention, 32x32x16 MFMA, swapped QK^T, no max-tracking.
// grid = (B*H, N/64); 128 threads = 2 waves; wave w owns q rows [q0+32w, +32).
// KV tiles of 64, double-buffered, T14 reg-staging, 1 barrier/iter.
// K: row-major XOR-swizzled, vector writes. V: transposed [d][kv] XOR-swizzled,
// scalar transpose writes (R3/R5-proven), bf16x8 B-frag reads.
__global__ __launch_bounds__(128)
void attn_kernel(const unsigned short* __restrict__ qkv,
                 const float* __restrict__ elev,
                 const float* __restrict__ alpha_p,
                 unsigned short* __restrict__ aout) {
  __shared__ __align__(16) unsigned short lds_k[2][64 * 64];   // [buf][kv][d] swz
  __shared__ __align__(16) unsigned short lds_vt[2][64 * 64];  // [buf][d][kv] swz
  __shared__ float lds_ej[2][64];
  __shared__ float lds_linv[2][32];

  const int t = threadIdx.x;
  const int l = t & 63;
  const int w = t >> 6;                    // 0..1
  const int l31 = l & 31;
  const int h = l >> 5;
  const int b = blockIdx.x / 12, hd = blockIdx.x % 12;
  const int qw = blockIdx.y * 64 + w * 32;

  const float cE = fmaxf(alpha_p[0], 0.f) * (1.4426950408889634f * 1e-3f);
  const float c1 = 0.18033688011112042f;   // 0.125 * log2(e)

  const size_t rs = 2304;
  const unsigned short* qbase = qkv + ((size_t)b * 2048) * rs + hd * 64;
  const unsigned short* kbase = qbase + 768;
  const unsigned short* vbase = qbase + 1536;

  bf16x8 qa[4];
  {
    const unsigned short* qp = qbase + (size_t)(qw + l31) * rs + h * 8;
#pragma unroll
    for (int ks = 0; ks < 4; ++ks) qa[ks] = *(const bf16x8*)(qp + ks * 16);
  }
  const float eiv = elev[(size_t)b * 2048 + qw + l31] * cE;

  // --- staging assignments (128 threads cover 64x64 K and V) ---
  // K: row kr, cols kc + 8i (i=0..3), vector b128 writes
  const int kr = w * 32 + (l >> 1);
  const int kc = (l & 1) * 32;
  // V: row vr, col half vh + 8i (i=0..3), scalar transpose writes
  const int vr = t >> 1;
  const int vh = (t & 1) * 32;

  uint4 rk[4], rv[4];
  float evn = 0.f;

  f32x16 o[2] = {};
  float psum = 0.f;

  // ---- prologue: stage tile 0 ----
#pragma unroll
  for (int i = 0; i < 4; ++i)
    rk[i] = *(const uint4*)(kbase + (size_t)kr * rs + kc + 8 * i);
#pragma unroll
  for (int i = 0; i < 4; ++i)
    rv[i] = *(const uint4*)(vbase + (size_t)vr * rs + vh + 8 * i);
  if (t < 64) evn = elev[(size_t)b * 2048 + t];
#pragma unroll
  for (int i = 0; i < 4; ++i)
    *(uint4*)&lds_k[0][kr * 64 + ((kc + 8 * i) ^ sw8(kr))] = rk[i];
#pragma unroll
  for (int i = 0; i < 4; ++i) {
    union { uint4 u; unsigned short s[8]; } vu; vu.u = rv[i];
#pragma unroll
    for (int j = 0; j < 8; ++j) {
      const int d = vh + 8 * i + j;
      lds_vt[0][d * 64 + (vr ^ sw8(d))] = vu.s[j];
    }
  }
  if (t < 64) lds_ej[0][t] = evn * cE;
  __syncthreads();

  for (int s = 0; s < 32; ++s) {
    const int cur = s & 1;
    const bool more = s < 31;
    if (more) {                    // prefetch tile s+1 into registers
      const int kvn = (s + 1) * 64;
#pragma unroll
      for (int i = 0; i < 4; ++i)
        rk[i] = *(const uint4*)(kbase + (size_t)(kvn + kr) * rs + kc + 8 * i);
#pragma unroll
      for (int i = 0; i < 4; ++i)
        rv[i] = *(const uint4*)(vbase + (size_t)(kvn + vr) * rs + vh + 8 * i);
      if (t < 64) evn = elev[(size_t)b * 2048 + kvn + t];
    }

    // --- S^T = K x Q ---
    f32x16 st[2] = {};
    __builtin_amdgcn_s_setprio(1);
#pragma unroll
    for (int kst = 0; kst < 4; ++kst) {
      const int col = kst * 16 + h * 8;
#pragma unroll
      for (int mb = 0; mb < 2; ++mb) {
        const int row = mb * 32 + l31;
        bf16x8 kf = *(const bf16x8*)&lds_k[cur][row * 64 + (col ^ sw8(row))];
        st[mb] = __builtin_amdgcn_mfma_f32_32x32x16_bf16(kf, qa[kst], st[mb], 0, 0, 0);
      }
    }
    __builtin_amdgcn_s_setprio(0);

    // --- softmax + in-register P pack ---
    bf16x8 pa[4];
#pragma unroll
    for (int mb = 0; mb < 2; ++mb) {
      float p16[16];
#pragma unroll
      for (int rr = 0; rr < 4; ++rr) {
        const float4 ejq = *(const float4*)&lds_ej[cur][mb * 32 + rr * 8 + h * 4];
#pragma unroll
        for (int jl = 0; jl < 4; ++jl) {
          const int r = rr * 4 + jl;
          const float bm = __builtin_amdgcn_fmed3f(ejq[jl] - eiv, 0.f, 14.4269504f);
          const float p = exp2v(__builtin_fmaf(st[mb][r], c1, -bm));
          p16[r] = p;
          psum += p;
        }
      }
#pragma unroll
      for (int ks2 = 0; ks2 < 2; ++ks2) {
        unsigned u0 = cvtpk(p16[ks2 * 8 + 0], p16[ks2 * 8 + 1]);
        unsigned u1 = cvtpk(p16[ks2 * 8 + 2], p16[ks2 * 8 + 3]);
        unsigned v0 = cvtpk(p16[ks2 * 8 + 4], p16[ks2 * 8 + 5]);
        unsigned v1 = cvtpk(p16[ks2 * 8 + 6], p16[ks2 * 8 + 7]);
        asm volatile("v_permlane32_swap_b32 %0, %1" : "+v"(u0), "+v"(v0));
        asm volatile("v_permlane32_swap_b32 %0, %1" : "+v"(u1), "+v"(v1));
        uint4 fr; fr.x = u0; fr.y = u1; fr.z = v0; fr.w = v1;
        pa[mb * 2 + ks2] = __builtin_bit_cast(bf16x8, fr);
      }
    }

    // --- O += P @ V ---
    __builtin_amdgcn_s_setprio(1);
#pragma unroll
    for (int ks = 0; ks < 4; ++ks) {
      const int col = ks * 16 + h * 8;
#pragma unroll
      for (int nb = 0; nb < 2; ++nb) {
        const int row = nb * 32 + l31;
        bf16x8 vf = *(const bf16x8*)&lds_vt[cur][row * 64 + (col ^ sw8(row))];
        o[nb] = __builtin_amdgcn_mfma_f32_32x32x16_bf16(pa[ks], vf, o[nb], 0, 0, 0);
      }
    }
    __builtin_amdgcn_s_setprio(0);

    // --- T14 late-write next tile ---
    if (more) {
      const int nxt = cur ^ 1;
#pragma unroll
      for (int i = 0; i < 4; ++i)
        *(uint4*)&lds_k[nxt][kr * 64 + ((kc + 8 * i) ^ sw8(kr))] = rk[i];
#pragma unroll
      for (int i = 0; i < 4; ++i) {
        union { uint4 u; unsigned short s[8]; } vu; vu.u = rv[i];
#pragma unroll
        for (int j = 0; j < 8; ++j) {
          const int d = vh + 8 * i + j;
          lds_vt[nxt][d * 64 + (vr ^ sw8(d))] = vu.s[j];
        }
      }
      if (t < 64) lds_ej[nxt][t] = evn * cE;
    }
    __syncthreads();
  }

  // --- epilogue: fold h halves of psum, broadcast 1/l, store bf16 ---
  psum += __shfl_xor(psum, 32, 64);
  if (h == 0) lds_linv[w][l31] = 1.0f / psum;
  __syncthreads();

#pragma unroll
  for (int nb = 0; nb < 2; ++nb) {
    const int col = hd * 64 + nb * 32 + l31;
#pragma unroll
    for (int rr = 0; rr < 4; ++rr) {
      const float4 lq = *(const float4*)&lds_linv[w][rr * 8 + h * 4];
#pragma unroll
      for (int jl = 0; jl < 4; ++jl) {
        const int q = qw + rr * 8 + h * 4 + jl;
        aout[((size_t)b * 2048 + q) * 768 + col] = f2bf(o[nb][rr * 4 + jl] * lq[jl]);
      }
    }
  }
}

extern "C" void kernel_launch(void* const* d_in, const int* in_sizes, int n_in,
                              void* d_out, int out_size, void* d_ws, size_t ws_size,
                              hipStream_t stream) {
  const float* x      = (const float*)d_in[0];   // [2,2048,768]
  const float* elev   = (const float*)d_in[1];   // [2,2048]
  const float* w_qkv  = (const float*)d_in[2];   // [2304,768]
  const float* w_proj = (const float*)d_in[3];   // [768,768]
  const float* b_proj = (const float*)d_in[4];   // [768]
  const float* alpha  = (const float*)d_in[5];   // [1]
  float* out = (float*)d_out;                    // [2,2048,768] f32

  unsigned short* qkvb   = (unsigned short*)d_ws;
  unsigned short* xb     = qkvb + (size_t)4096 * 2304;
  unsigned short* aob    = xb;                          // reuse after gemm1
  unsigned short* wqkvb  = xb + (size_t)4096 * 768;
  unsigned short* wprojb = wqkvb;                       // reuse after gemm1

  // converts: x + w_qkv in one launch
  cvt2_kernel<<<2400, 256, 0, stream>>>(x, xb, 4096 * 768 / 8,
                                        w_qkv, wqkvb, 2304 * 768 / 8);

  gemm_bt_bf16<false><<<dim3(32, 18), 256, 0, stream>>>(
      xb, wqkvb, nullptr, qkvb, 4096, 2304, 768);

  cvt_kernel<<<288, 256, 0, stream>>>(w_proj, wprojb, 768 * 768 / 8);

  attn_kernel<<<dim3(24, 32), 128, 0, stream>>>(qkvb, elev, alpha, aob);

  gemm_bt_bf16<true><<<dim3(32, 6), 256, 0, stream>>>(
      aob, wprojb, b_proj, out, 4096, 768, 768);
}

// Round 8
// 128.642 us; speedup vs baseline: 1.1188x; 1.0318x over previous
//
#include <hip/hip_runtime.h>

// PhysicsGuidedAttention: B=2, N=2048, D=768, H=12, Hd=64
// qkv = x @ w_qkv.T ; flash-attn with elevation bias ; out = attn_out @ w_proj.T + b_proj
// R8: attn = R3's measured-best kernel + grid-level KV-split x2 (768 blocks,
//     16 tiles each; no-max softmax => partials are pure sums). Half-1 partial
//     stored in d_out (f32, dead until gemm2), half-0 + psums in ws. Small
//     combine kernel -> aob. GEMMs = 2-phase dbuf (R4+), cvt x+wqkv merged.

typedef __attribute__((ext_vector_type(8))) short bf16x8;   // 8 bf16 = 4 VGPRs
typedef __attribute__((ext_vector_type(4))) float f32x4;
typedef __attribute__((ext_vector_type(16))) float f32x16;  // 32x32 accumulator

__device__ __forceinline__ unsigned short f2bf(float f) {
  unsigned int u = __builtin_bit_cast(unsigned int, f);
  u += 0x7fffu + ((u >> 16) & 1u);        // round-to-nearest-even
  return (unsigned short)(u >> 16);
}

__device__ __forceinline__ unsigned cvtpk(float lo, float hi) {
  unsigned r;
  asm("v_cvt_pk_bf16_f32 %0, %1, %2" : "=v"(r) : "v"(lo), "v"(hi));
  return r;
}

__device__ __forceinline__ float exp2v(float x) {
  float r;
  asm("v_exp_f32 %0, %1" : "=v"(r) : "v"(x));
  return r;
}

// XOR swizzle on element index: spreads 128B-stride row slots across banks.
__device__ __forceinline__ int sw8(int row) {
  return ((row ^ (row >> 3)) & 7) << 3;
}

__device__ __forceinline__ void gload16(const unsigned short* g, unsigned short* l) {
  __builtin_amdgcn_global_load_lds(
      (const __attribute__((address_space(1))) unsigned int*)g,
      (__attribute__((address_space(3))) unsigned int*)l, 16, 0, 0);
}

// ---------------------------------------------------------------------------
// f32 -> bf16 converts for x and w_qkv in one launch.
__global__ __launch_bounds__(256)
void cvt2_kernel(const float* __restrict__ a, unsigned short* __restrict__ ao, int na8,
                 const float* __restrict__ b, unsigned short* __restrict__ bo, int nb8) {
  int i = blockIdx.x * 256 + threadIdx.x;
  const float* src; unsigned short* dst;
  if (i < na8) { src = a; dst = ao; }
  else {
    i -= na8;
    if (i >= nb8) return;
    src = b; dst = bo;
  }
  const float4 f0 = ((const float4*)src)[i * 2];
  const float4 f1 = ((const float4*)src)[i * 2 + 1];
  uint4 v;
  v.x = (unsigned)f2bf(f0.x) | ((unsigned)f2bf(f0.y) << 16);
  v.y = (unsigned)f2bf(f0.z) | ((unsigned)f2bf(f0.w) << 16);
  v.z = (unsigned)f2bf(f1.x) | ((unsigned)f2bf(f1.y) << 16);
  v.w = (unsigned)f2bf(f1.z) | ((unsigned)f2bf(f1.w) << 16);
  ((uint4*)dst)[i] = v;
}

__global__ __launch_bounds__(256)
void cvt_kernel(const float* __restrict__ in, unsigned short* __restrict__ out, int n8) {
  const int i = blockIdx.x * 256 + threadIdx.x;
  if (i >= n8) return;
  const float4 f0 = ((const float4*)in)[i * 2];
  const float4 f1 = ((const float4*)in)[i * 2 + 1];
  uint4 v;
  v.x = (unsigned)f2bf(f0.x) | ((unsigned)f2bf(f0.y) << 16);
  v.y = (unsigned)f2bf(f0.z) | ((unsigned)f2bf(f0.w) << 16);
  v.z = (unsigned)f2bf(f1.x) | ((unsigned)f2bf(f1.y) << 16);
  v.w = (unsigned)f2bf(f1.z) | ((unsigned)f2bf(f1.w) << 16);
  ((uint4*)out)[i] = v;
}

// ---------------------------------------------------------------------------
// C[M,N] = A[M,K] @ B[N,K]^T, bf16, 128x128 tile, BK=32, 2-phase dbuf pipeline.
template<bool OUT_F32>
__global__ __launch_bounds__(256)
void gemm_bt_bf16(const unsigned short* __restrict__ Ap,
                  const unsigned short* __restrict__ Bp,
                  const float* __restrict__ bias, void* __restrict__ Cp,
                  int M, int N, int K) {
  __shared__ __align__(16) unsigned short lds_a[2][128 * 32];
  __shared__ __align__(16) unsigned short lds_b[2][128 * 32];
  const int t = threadIdx.x;
  const int l = t & 63;
  const int w = t >> 6;
  const int wr = w >> 1, wc = w & 1;
  const int brow = blockIdx.x * 128;
  const int bcol = blockIdx.y * 128;
  const int l15 = l & 15, l4 = l >> 4;

  const int srow = t >> 2;
  const int scol = (t & 3) * 8;
  const unsigned short* ga = Ap + (size_t)(brow + srow) * K + scol;
  const unsigned short* gb = Bp + (size_t)(bcol + srow) * K + scol;

  f32x4 acc[4][4] = {};
  const int nk = K >> 5;

  {
    unsigned short* la = lds_a[0] + w * 512;
    unsigned short* lb = lds_b[0] + w * 512;
    gload16(ga, la);
    gload16(ga + (size_t)64 * K, la + 2048);
    gload16(gb, lb);
    gload16(gb + (size_t)64 * K, lb + 2048);
  }
  __syncthreads();

  int buf = 0;
  for (int kt = 0; kt < nk; ++kt) {
    if (kt + 1 < nk) {
      const size_t ko = (size_t)(kt + 1) * 32;
      unsigned short* la = lds_a[buf ^ 1] + w * 512;
      unsigned short* lb = lds_b[buf ^ 1] + w * 512;
      gload16(ga + ko, la);
      gload16(ga + ko + (size_t)64 * K, la + 2048);
      gload16(gb + ko, lb);
      gload16(gb + ko + (size_t)64 * K, lb + 2048);
    }
    bf16x8 af[4], bfr[4];
#pragma unroll
    for (int i = 0; i < 4; ++i) {
      af[i]  = *(const bf16x8*)&lds_a[buf][(wr * 64 + i * 16 + l15) * 32 + l4 * 8];
      bfr[i] = *(const bf16x8*)&lds_b[buf][(wc * 64 + i * 16 + l15) * 32 + l4 * 8];
    }
#pragma unroll
    for (int i = 0; i < 4; ++i)
#pragma unroll
      for (int j = 0; j < 4; ++j)
        acc[i][j] = __builtin_amdgcn_mfma_f32_16x16x32_bf16(af[i], bfr[j], acc[i][j], 0, 0, 0);
    __syncthreads();
    buf ^= 1;
  }

#pragma unroll
  for (int i = 0; i < 4; ++i)
#pragma unroll
    for (int j = 0; j < 4; ++j)
#pragma unroll
      for (int r = 0; r < 4; ++r) {
        const int row = brow + wr * 64 + i * 16 + l4 * 4 + r;
        const int col = bcol + wc * 64 + j * 16 + l15;
        const float v = acc[i][j][r];
        if constexpr (OUT_F32) {
          ((float*)Cp)[(size_t)row * N + col] = v + bias[col];
        } else {
          ((unsigned short*)Cp)[(size_t)row * N + col] = f2bf(v);
        }
      }
}

// ---------------------------------------------------------------------------
// Flash attention (R3 structure), KV-split x2 across blockIdx.z.
// grid = (B*H, N/128, 2); 256 thr = 4 waves; wave w owns q [q0+32w, q0+32w+32).
// Half z processes KV tiles [16z, 16z+16). Partials: unnormalized O (f32) +
// psum per q-row; pure sums (no max-tracking) so halves combine by addition.
__global__ __launch_bounds__(256)
void attn_kernel(const unsigned short* __restrict__ qkv,
                 const float* __restrict__ elev,
                 const float* __restrict__ alpha_p,
                 float* __restrict__ O0, float* __restrict__ O1,
                 float* __restrict__ psums) {
  __shared__ __align__(16) unsigned short lds_k[2][64 * 64];
  __shared__ __align__(16) unsigned short lds_vt[2][64 * 64];   // [d][kv], swizzled
  __shared__ __align__(16) float lds_ej[2][64];

  const int t = threadIdx.x;
  const int l = t & 63;
  const int w = t >> 6;
  const int l31 = l & 31;
  const int h = l >> 5;
  const int b = blockIdx.x / 12, hd = blockIdx.x % 12;
  const int q0 = blockIdx.y * 128 + w * 32;
  const int z = blockIdx.z;
  const int s_lo = z * 16, s_hi = s_lo + 16;

  const float cE = fmaxf(alpha_p[0], 0.f) * (1.4426950408889634f * 1e-3f);
  const float c1 = 0.18033688011112042f;   // 0.125 * log2(e)

  const size_t rs = 2304;
  const unsigned short* qbase = qkv + ((size_t)b * 2048) * rs + hd * 64;
  const unsigned short* kbase = qbase + 768;
  const unsigned short* vbase = qbase + 1536;

  bf16x8 qa[4];
  {
    const unsigned short* qp = qbase + (size_t)(q0 + l31) * rs + h * 8;
#pragma unroll
    for (int ks = 0; ks < 4; ++ks) qa[ks] = *(const bf16x8*)(qp + ks * 16);
  }
  const float eiv = elev[(size_t)b * 2048 + q0 + l31] * cE;

  f32x16 o[2] = {};
  float psum = 0.f;

  const int sr = t >> 3;          // staging row 0..31
  const int sc = (t & 7) * 8;     // staging col

  uint4 rk[2], rv[2];
  float evn = 0.f;

  // prologue: stage first tile of this half
  {
    const int kv0 = s_lo * 64;
#pragma unroll
    for (int p = 0; p < 2; ++p) {
      const int r = p * 32 + sr;
      rk[p] = *(const uint4*)(kbase + (size_t)(kv0 + r) * rs + sc);
      rv[p] = *(const uint4*)(vbase + (size_t)(kv0 + r) * rs + sc);
    }
    if (t < 64) evn = elev[(size_t)b * 2048 + kv0 + t];
#pragma unroll
    for (int p = 0; p < 2; ++p) {
      const int r = p * 32 + sr;
      *(uint4*)&lds_k[0][r * 64 + (sc ^ sw8(r))] = rk[p];
      union { uint4 u; unsigned short s[8]; } vu; vu.u = rv[p];
#pragma unroll
      for (int j = 0; j < 8; ++j) {
        const int d = sc + j;
        lds_vt[0][d * 64 + (r ^ sw8(d))] = vu.s[j];
      }
    }
    if (t < 64) lds_ej[0][t] = evn * cE;
  }
  __syncthreads();

  for (int it = s_lo; it < s_hi; ++it) {
    const int cur = it & 1;                // s_lo even -> starts at buf 0
    const bool more = it + 1 < s_hi;
    if (more) {
      const int kv1 = (it + 1) * 64;
#pragma unroll
      for (int p = 0; p < 2; ++p) {
        const int r = kv1 + p * 32 + sr;
        rk[p] = *(const uint4*)(kbase + (size_t)r * rs + sc);
        rv[p] = *(const uint4*)(vbase + (size_t)r * rs + sc);
      }
      if (t < 64) evn = elev[(size_t)b * 2048 + kv1 + t];
    }

    // --- S^T = K x Q ---
    f32x16 st[2] = {};
    __builtin_amdgcn_s_setprio(1);
#pragma unroll
    for (int kst = 0; kst < 4; ++kst) {
      const int col = kst * 16 + h * 8;
#pragma unroll
      for (int mb = 0; mb < 2; ++mb) {
        const int row = mb * 32 + l31;
        bf16x8 kf = *(const bf16x8*)&lds_k[cur][row * 64 + (col ^ sw8(row))];
        st[mb] = __builtin_amdgcn_mfma_f32_32x32x16_bf16(kf, qa[kst], st[mb], 0, 0, 0);
      }
    }
    __builtin_amdgcn_s_setprio(0);

    // --- softmax (no max-tracking) + in-register P pack ---
    bf16x8 pa[4];
#pragma unroll
    for (int mb = 0; mb < 2; ++mb) {
      float p16[16];
#pragma unroll
      for (int rr = 0; rr < 4; ++rr) {
        const float4 ejq = *(const float4*)&lds_ej[cur][mb * 32 + rr * 8 + h * 4];
#pragma unroll
        for (int jl = 0; jl < 4; ++jl) {
          const int r = rr * 4 + jl;
          const float bm = __builtin_amdgcn_fmed3f(ejq[jl] - eiv, 0.f, 14.4269504f);
          const float p = exp2v(__builtin_fmaf(st[mb][r], c1, -bm));
          p16[r] = p;
          psum += p;
        }
      }
#pragma unroll
      for (int ks2 = 0; ks2 < 2; ++ks2) {
        unsigned u0 = cvtpk(p16[ks2 * 8 + 0], p16[ks2 * 8 + 1]);
        unsigned u1 = cvtpk(p16[ks2 * 8 + 2], p16[ks2 * 8 + 3]);
        unsigned v0 = cvtpk(p16[ks2 * 8 + 4], p16[ks2 * 8 + 5]);
        unsigned v1 = cvtpk(p16[ks2 * 8 + 6], p16[ks2 * 8 + 7]);
        asm volatile("v_permlane32_swap_b32 %0, %1" : "+v"(u0), "+v"(v0));
        asm volatile("v_permlane32_swap_b32 %0, %1" : "+v"(u1), "+v"(v1));
        uint4 fr; fr.x = u0; fr.y = u1; fr.z = v0; fr.w = v1;
        pa[mb * 2 + ks2] = __builtin_bit_cast(bf16x8, fr);
      }
    }

    // --- O += P @ V ---
    __builtin_amdgcn_s_setprio(1);
#pragma unroll
    for (int ks = 0; ks < 4; ++ks) {
      const int col = ks * 16 + h * 8;
#pragma unroll
      for (int nb = 0; nb < 2; ++nb) {
        const int row = nb * 32 + l31;
        bf16x8 vf = *(const bf16x8*)&lds_vt[cur][row * 64 + (col ^ sw8(row))];
        o[nb] = __builtin_amdgcn_mfma_f32_32x32x16_bf16(pa[ks], vf, o[nb], 0, 0, 0);
      }
    }
    __builtin_amdgcn_s_setprio(0);

    // --- write next tile ---
    if (more) {
      const int nxt = cur ^ 1;
#pragma unroll
      for (int p = 0; p < 2; ++p) {
        const int r = p * 32 + sr;
        *(uint4*)&lds_k[nxt][r * 64 + (sc ^ sw8(r))] = rk[p];
        union { uint4 u; unsigned short s[8]; } vu; vu.u = rv[p];
#pragma unroll
        for (int j = 0; j < 8; ++j) {
          const int d = sc + j;
          lds_vt[nxt][d * 64 + (r ^ sw8(d))] = vu.s[j];
        }
      }
      if (t < 64) lds_ej[nxt][t] = evn * cE;
      __syncthreads();
    }
  }

  // --- partial epilogue: fold h halves of psum; store psum + unnormalized O ---
  psum += __shfl_xor(psum, 32, 64);
  float* OD = z ? O1 : O0;
  if (h == 0)
    psums[z * (24 * 2048) + blockIdx.x * 2048 + q0 + l31] = psum;
#pragma unroll
  for (int nb = 0; nb < 2; ++nb) {
    const int col = hd * 64 + nb * 32 + l31;
#pragma unroll
    for (int rr = 0; rr < 4; ++rr)
#pragma unroll
      for (int jl = 0; jl < 4; ++jl) {
        const int q = q0 + rr * 8 + h * 4 + jl;
        OD[((size_t)b * 2048 + q) * 768 + col] = o[nb][rr * 4 + jl];
      }
  }
}

// ---------------------------------------------------------------------------
// Combine the two KV-halves: aob = bf16((O0+O1) / (l0+l1)). grid 4096 x 192.
__global__ __launch_bounds__(192)
void combine_kernel(const float* __restrict__ O0, const float* __restrict__ O1,
                    const float* __restrict__ psums, unsigned short* __restrict__ aob) {
  const int row = blockIdx.x;              // 0..4095 = b*2048+q
  const int b = row >> 11, q = row & 2047;
  const int c = threadIdx.x * 4;
  const int hd = c >> 6;
  const int pidx = (b * 12 + hd) * 2048 + q;
  const float inv = 1.0f / (psums[pidx] + psums[24 * 2048 + pidx]);
  const size_t off = (size_t)row * 768 + c;
  const float4 a = *(const float4*)&O0[off];
  const float4 d = *(const float4*)&O1[off];
  ushort4 r;
  r.x = f2bf((a.x + d.x) * inv);
  r.y = f2bf((a.y + d.y) * inv);
  r.z = f2bf((a.z + d.z) * inv);
  r.w = f2bf((a.w + d.w) * inv);
  *(ushort4*)&aob[off] = r;
}

extern "C" void kernel_launch(void* const* d_in, const int* in_sizes, int n_in,
                              void* d_out, int out_size, void* d_ws, size_t ws_size,
                              hipStream_t stream) {
  const float* x      = (const float*)d_in[0];   // [2,2048,768]
  const float* elev   = (const float*)d_in[1];   // [2,2048]
  const float* w_qkv  = (const float*)d_in[2];   // [2304,768]
  const float* w_proj = (const float*)d_in[3];   // [768,768]
  const float* b_proj = (const float*)d_in[4];   // [768]
  const float* alpha  = (const float*)d_in[5];   // [1]
  float* out = (float*)d_out;                    // [2,2048,768] f32

  // ws layout:
  //   qkvb  : bf16 [4096,2304]                           (18.9 MB)
  //   xb    : bf16 [4096,768]  -> reused as aob          ( 6.3 MB)
  //   wqkvb : bf16 [2304,768]  -> reused as wprojb       ( 3.5 MB)
  //   P0    : f32  [4096,768]  attn half-0 partial       (12.6 MB)
  //   psums : f32  [2][24*2048]                          ( 0.4 MB)
  // attn half-1 partial lives in d_out (f32, dead until gemm2).
  unsigned short* qkvb   = (unsigned short*)d_ws;
  unsigned short* xb     = qkvb + (size_t)4096 * 2304;
  unsigned short* aob    = xb;
  unsigned short* wqkvb  = xb + (size_t)4096 * 768;
  unsigned short* wprojb = wqkvb;
  float* P0    = (float*)(wqkvb + (size_t)2304 * 768);
  float* psums = P0 + (size_t)4096 * 768;

  cvt2_kernel<<<2400, 256, 0, stream>>>(x, xb, 4096 * 768 / 8,
                                        w_qkv, wqkvb, 2304 * 768 / 8);

  gemm_bt_bf16<false><<<dim3(32, 18), 256, 0, stream>>>(
      xb, wqkvb, nullptr, qkvb, 4096, 2304, 768);

  cvt_kernel<<<288, 256, 0, stream>>>(w_proj, wprojb, 768 * 768 / 8);

  attn_kernel<<<dim3(24, 16, 2), 256, 0, stream>>>(qkvb, elev, alpha,
                                                   P0, out, psums);

  combine_kernel<<<4096, 192, 0, stream>>>(P0, out, psums, aob);

  gemm_bt_bf16<true><<<dim3(32, 6), 256, 0, stream>>>(
      aob, wprojb, b_proj, out, 4096, 768, 768);
}